// Round 1
// baseline (22.005 us; speedup 1.0000x reference)
//
#include <hip/hip_runtime.h>

// Problem constants (reference: B=128, G=1024, D=128)
constexpr int Bq = 128;
constexpr int Gq = 1024;
constexpr int Dq = 128;
constexpr int CHUNK = 256;          // g-rows handled per block
constexpr int NC = Gq / CHUNK;      // 4 chunks per batch

__global__ void zero_kernel(float* __restrict__ out, int n) {
    int i = blockIdx.x * blockDim.x + threadIdx.x;
    if (i < n) out[i] = 0.0f;
}

__global__ __launch_bounds__(256) void agg_kernel(
    const float* __restrict__ h,     // (B, G, D)
    const float* __restrict__ adj,   // (B, G, G)
    const int*   __restrict__ phone, // (B,)
    float*       __restrict__ out)   // (2, B, D) concatenated: g_bf then g_af
{
    const int b = blockIdx.x;   // batch
    const int c = blockIdx.y;   // g-chunk
    const int t = threadIdx.x;  // 0..255
    const int p = phone[b];

    // Stage this chunk's slice of the pivot row adj[b, p, c*CHUNK : (c+1)*CHUNK]
    __shared__ float row_s[CHUNK];
    {
        const long long rowbase =
            ((long long)b * Gq + (long long)p) * Gq + (long long)c * CHUNK;
        row_s[t] = adj[rowbase + t];
    }
    __syncthreads();

    // Thread t handles d = 4*(t&31) .. +3 for rows g ≡ (t>>5) (mod 8)
    const int rgrp = t >> 5;          // 0..7
    const int d4   = (t & 31) << 2;   // 0..124, step 4
    const int g0   = c * CHUNK;
    const float* hb = h + (long long)b * Gq * Dq;

    float4 bf = make_float4(0.f, 0.f, 0.f, 0.f);
    float4 af = make_float4(0.f, 0.f, 0.f, 0.f);

    #pragma unroll 4
    for (int gg = rgrp; gg < CHUNK; gg += 8) {
        const int g = g0 + gg;
        const float w = row_s[gg];
        const float4 v =
            *reinterpret_cast<const float4*>(hb + (long long)g * Dq + d4);
        const float wb = (g < p) ? w : 0.0f;  // strictly before pivot
        const float wa = (g > p) ? w : 0.0f;  // strictly after pivot
        bf.x = fmaf(wb, v.x, bf.x);
        bf.y = fmaf(wb, v.y, bf.y);
        bf.z = fmaf(wb, v.z, bf.z);
        bf.w = fmaf(wb, v.w, bf.w);
        af.x = fmaf(wa, v.x, af.x);
        af.y = fmaf(wa, v.y, af.y);
        af.z = fmaf(wa, v.z, af.z);
        af.w = fmaf(wa, v.w, af.w);
    }

    // Reduce the 8 row-groups per d-slice via LDS
    __shared__ float4 red_bf[256];
    __shared__ float4 red_af[256];
    red_bf[t] = bf;
    red_af[t] = af;
    __syncthreads();

    if (rgrp == 0) {  // t < 32: each thread owns one d4 slice
        float4 sb = red_bf[t];
        float4 sa = red_af[t];
        #pragma unroll
        for (int r = 1; r < 8; ++r) {
            const float4 ob = red_bf[t + 32 * r];
            const float4 oa = red_af[t + 32 * r];
            sb.x += ob.x; sb.y += ob.y; sb.z += ob.z; sb.w += ob.w;
            sa.x += oa.x; sa.y += oa.y; sa.z += oa.z; sa.w += oa.w;
        }
        float* obf = out + (long long)b * Dq + d4;            // g_bf
        float* oaf = out + (long long)Bq * Dq + (long long)b * Dq + d4; // g_af
        atomicAdd(&obf[0], sb.x);
        atomicAdd(&obf[1], sb.y);
        atomicAdd(&obf[2], sb.z);
        atomicAdd(&obf[3], sb.w);
        atomicAdd(&oaf[0], sa.x);
        atomicAdd(&oaf[1], sa.y);
        atomicAdd(&oaf[2], sa.z);
        atomicAdd(&oaf[3], sa.w);
    }
}

extern "C" void kernel_launch(void* const* d_in, const int* in_sizes, int n_in,
                              void* d_out, int out_size, void* d_ws, size_t ws_size,
                              hipStream_t stream) {
    const float* h     = (const float*)d_in[0];
    const float* adj   = (const float*)d_in[1];
    const int*   phone = (const int*)d_in[2];
    float* out = (float*)d_out;

    // d_out is poisoned (0xAA) and never re-zeroed between replays:
    // zero it ourselves every call (we accumulate with atomics).
    const int n = 2 * Bq * Dq;  // 32768
    zero_kernel<<<(n + 255) / 256, 256, 0, stream>>>(out, n);

    dim3 grid(Bq, NC);
    agg_kernel<<<grid, 256, 0, stream>>>(h, adj, phone, out);
}

// Round 2
// 16.166 us; speedup vs baseline: 1.3612x; 1.3612x over previous
//
#include <hip/hip_runtime.h>

// B=128, G=1024, D=128. Outputs: g_bf (B,D) then g_af (B,D), f32.
constexpr int Bq = 128;
constexpr int Gq = 1024;
constexpr int Dq = 128;
constexpr int NDC = 8;  // d-chunks of 16 floats (64 B) each -> grid 128 x 8

__global__ __launch_bounds__(256) void agg_kernel(
    const float* __restrict__ h,     // (B, G, D)
    const float* __restrict__ adj,   // (B, G, G)
    const int*   __restrict__ phone, // (B,)
    float*       __restrict__ out)   // [g_bf (B,D) | g_af (B,D)]
{
    const int b  = blockIdx.x;   // batch
    const int dc = blockIdx.y;   // d-chunk (16 floats)
    const int t  = threadIdx.x;  // 0..255
    const int p  = phone[b];

    // Stage the full pivot row adj[b, p, :] (4 KiB) -- coalesced float4.
    __shared__ float row_s[Gq];
    {
        const float4 r = *reinterpret_cast<const float4*>(
            adj + ((long long)b * Gq + (long long)p) * Gq + (t << 2));
        *reinterpret_cast<float4*>(row_s + (t << 2)) = r;
    }
    __syncthreads();

    // Thread t: d-slot (t&3) within this block's 16-float slice,
    // row-group t>>2 (64 groups), 16 rows per thread.
    const int dbase = dc * 16 + ((t & 3) << 2);
    const int rgrp  = t >> 2;  // 0..63
    const float* hb = h + (long long)b * Gq * Dq;

    float4 bf = make_float4(0.f, 0.f, 0.f, 0.f);
    float4 af = make_float4(0.f, 0.f, 0.f, 0.f);

    #pragma unroll 4
    for (int it = 0; it < Gq / 64; ++it) {
        const int g = rgrp + (it << 6);
        const float w = row_s[g];
        const float4 v =
            *reinterpret_cast<const float4*>(hb + g * Dq + dbase);
        const float wb = (g < p) ? w : 0.0f;  // strictly before pivot
        const float wa = (g > p) ? w : 0.0f;  // strictly after pivot
        bf.x = fmaf(wb, v.x, bf.x);
        bf.y = fmaf(wb, v.y, bf.y);
        bf.z = fmaf(wb, v.z, bf.z);
        bf.w = fmaf(wb, v.w, bf.w);
        af.x = fmaf(wa, v.x, af.x);
        af.y = fmaf(wa, v.y, af.y);
        af.z = fmaf(wa, v.z, af.z);
        af.w = fmaf(wa, v.w, af.w);
    }

    // Wave-level reduce across lane bits 2..5 (row-groups within wave).
    #pragma unroll
    for (int m = 4; m <= 32; m <<= 1) {
        bf.x += __shfl_xor(bf.x, m, 64);
        bf.y += __shfl_xor(bf.y, m, 64);
        bf.z += __shfl_xor(bf.z, m, 64);
        bf.w += __shfl_xor(bf.w, m, 64);
        af.x += __shfl_xor(af.x, m, 64);
        af.y += __shfl_xor(af.y, m, 64);
        af.z += __shfl_xor(af.z, m, 64);
        af.w += __shfl_xor(af.w, m, 64);
    }

    // Cross-wave combine (4 waves) via tiny LDS buffers.
    __shared__ float4 pbf[4][4];
    __shared__ float4 paf[4][4];
    const int wave = t >> 6;
    const int lane = t & 63;
    if (lane < 4) {
        pbf[wave][lane] = bf;
        paf[wave][lane] = af;
    }
    __syncthreads();

    if (t < 4) {  // thread t owns d-slot t of this block's slice
        float4 sb = pbf[0][t];
        float4 sa = paf[0][t];
        #pragma unroll
        for (int wv = 1; wv < 4; ++wv) {
            const float4 ob = pbf[wv][t];
            const float4 oa = paf[wv][t];
            sb.x += ob.x; sb.y += ob.y; sb.z += ob.z; sb.w += ob.w;
            sa.x += oa.x; sa.y += oa.y; sa.z += oa.z; sa.w += oa.w;
        }
        const int d = dc * 16 + (t << 2);
        *reinterpret_cast<float4*>(out + b * Dq + d) = sb;
        *reinterpret_cast<float4*>(out + Bq * Dq + b * Dq + d) = sa;
    }
}

extern "C" void kernel_launch(void* const* d_in, const int* in_sizes, int n_in,
                              void* d_out, int out_size, void* d_ws, size_t ws_size,
                              hipStream_t stream) {
    const float* h     = (const float*)d_in[0];
    const float* adj   = (const float*)d_in[1];
    const int*   phone = (const int*)d_in[2];
    float* out = (float*)d_out;

    dim3 grid(Bq, NDC);
    agg_kernel<<<grid, 256, 0, stream>>>(h, adj, phone, out);
}